// Round 6
// baseline (282.632 us; speedup 1.0000x reference)
//
#include <hip/hip_runtime.h>

constexpr int IMW  = 96;
constexpr int NPIX = 9216;
constexpr int TB   = 256;            // threads per block
constexpr int JT   = 4;              // j's per thread
constexpr int JB   = NPIX/(TB*JT);   // 9 j-blocks
constexpr int SI   = 96;             // staged i's per segment (1 image row)
constexpr int NSEG = NPIX/SI;        // 96 segments
constexpr int NBIL = JB*NSEG;        // 864 blocks
constexpr int NUPD = NPIX/TB;        // 36 blocks (epilogue)

constexpr float LCLIP = 18.420681f;               // -log(1e-8)
constexpr float LOG2E = 1.4426950408889634f;
constexpr float C1 = -LOG2E/18.0f;                // gaussian (sxy=3), base-2
constexpr float C2 = -LOG2E/5000.0f;              // bilateral spatial (sxy=50)
constexpr float C3 = -LOG2E/400.0f;               // bilateral feature (2*df^2/(2*20^2))

// One launch = one mean-field iteration. Segment = ONE image row (SI=96).
// MODE 0: q_t from mask; also writes pksum (column sums of Kfull).
// MODE 1: q_t reconstructed per-block from previous launch's partials.
// pcur[seg][j] = sum_{i in seg} q_t[i] * Kfull[i,j]   (diag included, =13)
//             = [bilateral dense loop] + gy(seg,yj) * conv[xj]
template<int MODE>
__global__ __launch_bounds__(TB) void k_iter(const float* __restrict__ img,
                                             const int* __restrict__ mask,
                                             const float* __restrict__ pprev,
                                             float* __restrict__ pcur,
                                             float* __restrict__ pksum,
                                             const float* __restrict__ qprev,
                                             float* __restrict__ qcur){
    __shared__ float4 st[SI];          // {f_i, C2*x^2+C3*f^2, 10*q_i, q_i}
    __shared__ float  wg[192];         // 3*exp2(C1*d^2), d = idx-95
    __shared__ float  pm[2][SI], pk2[2][SI];
    __shared__ float  conv[SI];        // gaussian 1D conv of q (incl. compat 3)
    __shared__ float  sx3[SI];         // row-sum of wg (MODE0 only)
    const int tid = threadIdx.x;
    const int jb  = blockIdx.x / NSEG;
    const int seg = blockIdx.x % NSEG;
    const int i0  = seg * SI;

    if (tid < 192){
        float d = (float)(tid - 95);
        wg[tid] = 3.0f * exp2f(C1 * d * d);
    }

    // ---- phase 1: q_t for this block's staged row ----
    if (MODE == 1){
        if (tid < 2*SI){
            int  ii   = (tid < SI) ? tid : tid - SI;
            int  half = (tid >= SI);
            int  i    = i0 + ii;
            const float* pp = pprev + (size_t)half*48*NPIX + i;
            const float* ps = pksum + (size_t)half*48*NPIX + i;
            float m = 0.f, kk = 0.f;
            #pragma unroll
            for (int s = 0; s < 48; ++s){ m += pp[s*NPIX]; kk += ps[s*NPIX]; }
            pm[half][ii] = m; pk2[half][ii] = kk;
        }
        __syncthreads();
    }
    if (tid < SI){
        int i = i0 + tid;
        float fi = img[i];
        float qi;
        if (MODE == 0){
            qi = (mask[i] == 0) ? (1.0f/(1.0f + __expf( LCLIP)))
                                : (1.0f/(1.0f + __expf(-LCLIP)));
        } else {
            float m  = pm[0][tid] + pm[1][tid];
            float kk = pk2[0][tid] + pk2[1][tid];
            float duv = (mask[i] == 0) ? LCLIP : -LCLIP;
            float mnd = m - 13.0f * qprev[i];              // remove diagonal
            float delta = duv + (kk - 13.0f) - 2.0f*mnd;
            qi = 1.0f/(1.0f + __expf(delta));
        }
        float xf = (float)tid;
        st[tid] = make_float4(fi, fmaf(C2*xf, xf, C3*fi*fi), 10.0f*qi, qi);
        if (jb == 0) qcur[i] = qi;                         // designated writer
    }
    __syncthreads();

    // ---- phase 2: per-block gaussian 1D conv (shared across all j with same xj) ----
    if (tid < SI){
        float c = 0.f, sw = 0.f;
        #pragma unroll 4
        for (int xp = 0; xp < IMW; ++xp){
            float w = wg[tid - xp + 95];
            c = fmaf(st[xp].w, w, c);
            if (MODE == 0) sw += w;
        }
        conv[tid] = c;
        if (MODE == 0) sx3[tid] = sw;
    }

    // ---- per-j setup ----
    float gx[JT], gf[JT], rc[JT], gy[JT];
    int   xji[JT];
    const float ryf = (float)seg;
    #pragma unroll
    for (int k = 0; k < JT; ++k){
        int j = jb*(TB*JT) + k*TB + tid;
        int xi = j % IMW, yi = j / IMW;
        xji[k] = xi;
        float xjf = (float)xi;
        float fj  = img[j];
        gx[k] = -2.0f*C2*xjf;
        gf[k] = -2.0f*C3*fj;
        float bb = fmaf(C2*xjf, xjf, C3*fj*fj);
        float dy = ryf - (float)yi;
        rc[k] = fmaf(C2*dy, dy, bb);
        gy[k] = exp2f(C1*dy*dy);
    }
    __syncthreads();

    // ---- phase 3: dense bilateral partial matvec (pure: 4 VALU + 1 exp2 / pair) ----
    float acc[JT] = {0,0,0,0};
    float ak [JT] = {0,0,0,0};
    float xf = 0.f;
    #pragma unroll 4
    for (int x = 0; x < IMW; ++x){
        float4 s = st[x];                                  // wave-uniform broadcast
        #pragma unroll
        for (int k = 0; k < JT; ++k){
            float h = s.y + rc[k];
            h = fmaf(xf,  gx[k], h);
            h = fmaf(s.x, gf[k], h);
            float e = exp2f(h);                            // bilateral kernel value
            acc[k] = fmaf(s.z, e, acc[k]);                 // += 10*q_i*e
            if (MODE == 0) ak[k] += e;
        }
        xf += 1.0f;
    }

    // ---- fold gaussian + store partials ----
    #pragma unroll
    for (int k = 0; k < JT; ++k){
        int j = jb*(TB*JT) + k*TB + tid;
        pcur[seg*NPIX + j] = fmaf(gy[k], conv[xji[k]], acc[k]);
        if (MODE == 0)
            pksum[seg*NPIX + j] = fmaf(10.0f, ak[k], gy[k]*sx3[xji[k]]);
    }
}

// epilogue: final reduction + argmax
__global__ __launch_bounds__(TB) void k_final(const int* __restrict__ mask,
                                              const float* __restrict__ pmsg,
                                              const float* __restrict__ pksum,
                                              const float* __restrict__ qprev,
                                              float* __restrict__ out){
    int j = blockIdx.x*TB + threadIdx.x;
    float m = 0.f, kk = 0.f;
    #pragma unroll
    for (int s = 0; s < NSEG; ++s){
        m  += pmsg[s*NPIX + j];
        kk += pksum[s*NPIX + j];
    }
    float duv = (mask[j] == 0) ? LCLIP : -LCLIP;
    float mnd = m - 13.0f*qprev[j];
    float delta = duv + (kk - 13.0f) - 2.0f*mnd;
    out[j] = (delta > 0.f) ? 1.0f : 0.0f;                  // argmax; tie -> label 0
}

extern "C" void kernel_launch(void* const* d_in, const int* in_sizes, int n_in,
                              void* d_out, int out_size, void* d_ws, size_t ws_size,
                              hipStream_t stream){
    const float* img  = (const float*)d_in[0];
    const int*   mask = (const int*)d_in[1];
    float* out = (float*)d_out;
    float* ws  = (float*)d_ws;

    float* pmsgA = ws;                              // partials, even iters
    float* pmsgB = pmsgA + (size_t)NSEG*NPIX;       // partials, odd iters
    float* pksum = pmsgB + (size_t)NSEG*NPIX;       // column sums of Kfull
    float* qA    = pksum + (size_t)NSEG*NPIX;       // q, even iters
    float* qB    = qA + NPIX;

    dim3 g(NBIL), b(TB);
    // t=0: q_0 from mask; writes pmsgA, pksum, qA
    k_iter<0><<<g, b, 0, stream>>>(img, mask, nullptr, pmsgA, pksum, nullptr, qA);
    // t=1..4: reconstruct q_t from prev partials, write new partials
    k_iter<1><<<g, b, 0, stream>>>(img, mask, pmsgA, pmsgB, pksum, qA, qB);
    k_iter<1><<<g, b, 0, stream>>>(img, mask, pmsgB, pmsgA, pksum, qB, qA);
    k_iter<1><<<g, b, 0, stream>>>(img, mask, pmsgA, pmsgB, pksum, qA, qB);
    k_iter<1><<<g, b, 0, stream>>>(img, mask, pmsgB, pmsgA, pksum, qB, qA);
    // final update (iteration 5) + argmax
    k_final<<<dim3(NUPD), b, 0, stream>>>(mask, pmsgA, pksum, qA, out);
}

// Round 7
// 179.832 us; speedup vs baseline: 1.5716x; 1.5716x over previous
//
#include <hip/hip_runtime.h>

constexpr int IMW  = 96;
constexpr int NPIX = 9216;
constexpr int TB   = 256;            // threads per block
constexpr int JT   = 2;              // j's per thread
constexpr int JB   = NPIX/(TB*JT);   // 18 j-blocks
constexpr int SI   = 192;            // staged i's per segment (2 rows)
constexpr int NSEG = NPIX/SI;        // 48 segments (footprint L2-resident)
constexpr int NBIL = JB*NSEG;        // 864 blocks = 3456 waves (~42% occ)
constexpr int NUPD = NPIX/TB;        // 36 blocks (epilogue)

constexpr float LCLIP = 18.420681f;               // -log(1e-8)
constexpr float LOG2E = 1.4426950408889634f;
constexpr float C1 = -LOG2E/18.0f;                // gaussian (sxy=3), base-2
constexpr float C2 = -LOG2E/5000.0f;              // bilateral spatial (sxy=50)
constexpr float C3 = -LOG2E/400.0f;               // bilateral feature (2*df^2/(2*20^2))

// One launch = one mean-field iteration. Segment = 2 image rows (SI=192).
// MODE 0: q_t from mask; also writes pksum (per-seg partial column sums of Kfull).
// MODE 1: q_t reconstructed from prev partials; reduces pksum and PERSISTS ksum.
// MODE 2: q_t reconstructed; reads reduced ksum (1 load instead of 48).
// pcur[seg][j] = sum_{i in seg} q_t[i]*Kfull[i,j]  (diag incl, =13)
//             = [dense bilateral] + gy0*conv0[xj] + gy1*conv1[xj]
template<int MODE>
__global__ __launch_bounds__(TB) void k_iter(const float* __restrict__ img,
                                             const int* __restrict__ mask,
                                             const float* __restrict__ pprev,
                                             float* __restrict__ pcur,
                                             float* __restrict__ pksum,
                                             float* __restrict__ ksum,
                                             const float* __restrict__ qprev,
                                             float* __restrict__ qcur){
    __shared__ float4 st[2][IMW];      // per row: {f, C2x^2+C3f^2, 10q, q}
    __shared__ float  wg[192];         // 3*exp2(C1*d^2), d = idx-95
    __shared__ float  conv[2][IMW];    // per-row gaussian 1D conv of q
    __shared__ float  sx3[IMW];        // row-sum of wg (MODE0 only)
    const int tid = threadIdx.x;
    const int jb  = blockIdx.x / NSEG;
    const int seg = blockIdx.x % NSEG;
    const int i0  = seg * SI;

    if (tid < 192){
        float d = (float)(tid - 95);
        wg[tid] = 3.0f * exp2f(C1*d*d);
    }

    // ---- phase 1: q_t at this block's 192 staged i's ----
    if (tid < SI){
        int i = i0 + tid;
        float fi = img[i];
        float qi;
        if (MODE == 0){
            qi = (mask[i]==0) ? 1.0f/(1.0f+__expf( LCLIP))
                              : 1.0f/(1.0f+__expf(-LCLIP));
        } else {
            float m = 0.f;
            #pragma unroll
            for (int s = 0; s < NSEG; ++s) m += pprev[s*NPIX + i];
            float kk;
            if (MODE == 1){
                kk = 0.f;
                #pragma unroll
                for (int s = 0; s < NSEG; ++s) kk += pksum[s*NPIX + i];
                if (jb == 0) ksum[i] = kk;             // persist (iteration-invariant)
            } else {
                kk = ksum[i];
            }
            float duv = (mask[i]==0) ? LCLIP : -LCLIP;
            float mnd = m - 13.0f*qprev[i];            // remove diagonal
            float delta = duv + (kk - 13.0f) - 2.0f*mnd;
            qi = 1.0f/(1.0f+__expf(delta));
        }
        float xf = (float)(tid % IMW);
        st[tid/IMW][tid%IMW] = make_float4(fi, fmaf(C2*xf, xf, C3*fi*fi), 10.0f*qi, qi);
        if (jb == 0) qcur[i] = qi;                     // designated writer
    }

    // ---- per-j setup (no LDS dependence; overlaps barrier) ----
    float gx[JT], gf[JT], rc0[JT], rc1[JT], gy0[JT], gy1[JT];
    int xji[JT];
    #pragma unroll
    for (int k = 0; k < JT; ++k){
        int j  = jb*(TB*JT) + k*TB + tid;
        int xi = j % IMW, yi = j / IMW;
        xji[k] = xi;
        float xjf = (float)xi, fj = img[j];
        gx[k] = -2.0f*C2*xjf;
        gf[k] = -2.0f*C3*fj;
        float bb  = fmaf(C2*xjf, xjf, C3*fj*fj);
        float dy0 = (float)(2*seg    ) - (float)yi;
        float dy1 = (float)(2*seg + 1) - (float)yi;
        rc0[k] = fmaf(C2*dy0, dy0, bb);
        rc1[k] = fmaf(C2*dy1, dy1, bb);
        gy0[k] = exp2f(C1*dy0*dy0);
        gy1[k] = exp2f(C1*dy1*dy1);
    }
    __syncthreads();

    // ---- phase 2: per-row gaussian 1D conv (shared across all j with same xj) ----
    if (tid < 192){
        int r = tid / IMW, x = tid - r*IMW;
        float c = 0.f;
        #pragma unroll 4
        for (int xp = 0; xp < IMW; ++xp)
            c = fmaf(st[r][xp].w, wg[x - xp + 95], c);
        conv[r][x] = c;
        if (MODE == 0 && r == 0){
            float sw = 0.f;
            #pragma unroll 4
            for (int xp = 0; xp < IMW; ++xp) sw += wg[x - xp + 95];
            sx3[x] = sw;
        }
    }
    __syncthreads();

    // ---- phase 3: dense bilateral partial matvec (4 VALU + 1 exp2 per pair) ----
    float acc[JT] = {0,0}, ak[JT] = {0,0};
    float xf = 0.f;
    #pragma unroll 4
    for (int x = 0; x < IMW; ++x){
        float4 s = st[0][x];                           // wave-uniform broadcast
        #pragma unroll
        for (int k = 0; k < JT; ++k){
            float h = s.y + rc0[k];
            h = fmaf(xf,  gx[k], h);
            h = fmaf(s.x, gf[k], h);
            float e = exp2f(h);
            acc[k] = fmaf(s.z, e, acc[k]);
            if (MODE == 0) ak[k] += e;
        }
        xf += 1.f;
    }
    xf = 0.f;
    #pragma unroll 4
    for (int x = 0; x < IMW; ++x){
        float4 s = st[1][x];
        #pragma unroll
        for (int k = 0; k < JT; ++k){
            float h = s.y + rc1[k];
            h = fmaf(xf,  gx[k], h);
            h = fmaf(s.x, gf[k], h);
            float e = exp2f(h);
            acc[k] = fmaf(s.z, e, acc[k]);
            if (MODE == 0) ak[k] += e;
        }
        xf += 1.f;
    }

    // ---- fold gaussian + store partials ----
    #pragma unroll
    for (int k = 0; k < JT; ++k){
        int j = jb*(TB*JT) + k*TB + tid;
        float v = acc[k];
        v = fmaf(gy0[k], conv[0][xji[k]], v);
        v = fmaf(gy1[k], conv[1][xji[k]], v);
        pcur[seg*NPIX + j] = v;
        if (MODE == 0)
            pksum[seg*NPIX + j] = fmaf(10.0f, ak[k], (gy0[k]+gy1[k])*sx3[xji[k]]);
    }
}

// epilogue: final reduction + argmax
__global__ __launch_bounds__(TB) void k_final(const int* __restrict__ mask,
                                              const float* __restrict__ pmsg,
                                              const float* __restrict__ ksum,
                                              const float* __restrict__ qprev,
                                              float* __restrict__ out){
    int j = blockIdx.x*TB + threadIdx.x;
    float m = 0.f;
    #pragma unroll
    for (int s = 0; s < NSEG; ++s) m += pmsg[s*NPIX + j];
    float duv = (mask[j]==0) ? LCLIP : -LCLIP;
    float mnd = m - 13.0f*qprev[j];
    float delta = duv + (ksum[j] - 13.0f) - 2.0f*mnd;
    out[j] = (delta > 0.f) ? 1.0f : 0.0f;              // argmax; tie -> label 0
}

extern "C" void kernel_launch(void* const* d_in, const int* in_sizes, int n_in,
                              void* d_out, int out_size, void* d_ws, size_t ws_size,
                              hipStream_t stream){
    const float* img  = (const float*)d_in[0];
    const int*   mask = (const int*)d_in[1];
    float* out = (float*)d_out;
    float* ws  = (float*)d_ws;

    float* pmsgA = ws;                              // partials, even iters
    float* pmsgB = pmsgA + (size_t)NSEG*NPIX;       // partials, odd iters
    float* pksum = pmsgB + (size_t)NSEG*NPIX;       // per-seg column sums of Kfull
    float* qA    = pksum + (size_t)NSEG*NPIX;
    float* qB    = qA + NPIX;
    float* ksum  = qB + NPIX;                       // reduced column sums (persisted)

    dim3 g(NBIL), b(TB);
    // t=0: q_0 from mask; writes pmsgA, pksum, qA
    k_iter<0><<<g, b, 0, stream>>>(img, mask, nullptr, pmsgA, pksum, ksum, nullptr, qA);
    // t=1: full reconstruction (reduces pksum, persists ksum)
    k_iter<1><<<g, b, 0, stream>>>(img, mask, pmsgA, pmsgB, pksum, ksum, qA, qB);
    // t=2..4: slim reconstruction (reads reduced ksum)
    k_iter<2><<<g, b, 0, stream>>>(img, mask, pmsgB, pmsgA, pksum, ksum, qB, qA);
    k_iter<2><<<g, b, 0, stream>>>(img, mask, pmsgA, pmsgB, pksum, ksum, qA, qB);
    k_iter<2><<<g, b, 0, stream>>>(img, mask, pmsgB, pmsgA, pksum, ksum, qB, qA);
    // t=5: final update + argmax
    k_final<<<dim3(NUPD), b, 0, stream>>>(mask, pmsgA, ksum, qA, out);
}

// Round 8
// 173.273 us; speedup vs baseline: 1.6311x; 1.0379x over previous
//
#include <hip/hip_runtime.h>

constexpr int IMW  = 96;
constexpr int NPIX = 9216;
constexpr int TB   = 256;            // threads per block
constexpr int JB   = NPIX/TB;        // 36 j-blocks (JT=1)
constexpr int SI   = 192;            // staged i's per segment (2 rows)
constexpr int NSEG = NPIX/SI;        // 48 segments (partials stay L2-resident)
constexpr int NBIL = JB*NSEG;        // 1728 blocks = 6912 waves
constexpr int NUPD = NPIX/TB;        // 36 blocks (epilogue)

constexpr float LCLIP = 18.420681f;               // -log(1e-8)
constexpr float LOG2E = 1.4426950408889634f;
constexpr float C1 = -LOG2E/18.0f;                // gaussian (sxy=3), base-2
constexpr float C2 = -LOG2E/5000.0f;              // bilateral spatial (sxy=50)
constexpr float C3 = -LOG2E/400.0f;               // bilateral feature (2*df^2/(2*20^2))

// software exp2: VALU-only (the hw v_exp_f32 trans pipe is ~64 cyc/wave64 and
// is the whole-kernel bottleneck). rndne+sub+7*fma+cvt+ldexp ~= 10 VALU.
// deg-6 Taylor on [-0.5,0.5]: rel err ~1.2e-7. ldexp handles underflow (n<-126 -> 0).
__device__ __forceinline__ float fexp2(float a){
    float n = rintf(a);
    float f = a - n;
    float p =             1.5403530e-4f;
    p = fmaf(p, f, 1.3333558e-3f);
    p = fmaf(p, f, 9.6181291e-3f);
    p = fmaf(p, f, 5.5504109e-2f);
    p = fmaf(p, f, 2.4022651e-1f);
    p = fmaf(p, f, 6.9314718e-1f);
    p = fmaf(p, f, 1.0f);
    return ldexpf(p, (int)n);
}

// One launch = one mean-field iteration. Segment = 2 image rows (SI=192).
// MODE 0: q_t from mask; also writes pksum (per-seg partial column sums of Kfull).
// MODE 1: q_t reconstructed from prev partials; reduces pksum and PERSISTS ksum.
// MODE 2: q_t reconstructed; reads reduced ksum (1 load instead of 48).
// pcur[seg][j] = sum_{i in seg} q_t[i]*Kfull[i,j]  (diag incl, =13)
//             = [dense bilateral] + gy0*conv0[xj] + gy1*conv1[xj]
template<int MODE>
__global__ __launch_bounds__(TB) void k_iter(const float* __restrict__ img,
                                             const int* __restrict__ mask,
                                             const float* __restrict__ pprev,
                                             float* __restrict__ pcur,
                                             float* __restrict__ pksum,
                                             float* __restrict__ ksum,
                                             const float* __restrict__ qprev,
                                             float* __restrict__ qcur){
    __shared__ float4 st[2][IMW];      // per row: {f, C2x^2+C3f^2, 10q, q}
    __shared__ float  wg[192];         // 3*exp2(C1*d^2), d = idx-95
    __shared__ float  conv[2][IMW];    // per-row gaussian 1D conv of q
    __shared__ float  sx3[IMW];        // row-sum of wg (MODE0 only)
    const int tid = threadIdx.x;
    const int jb  = blockIdx.x / NSEG;
    const int seg = blockIdx.x % NSEG;
    const int i0  = seg * SI;

    if (tid < 192){
        float d = (float)(tid - 95);
        wg[tid] = 3.0f * exp2f(C1*d*d);
    }

    // ---- phase 1: q_t at this block's 192 staged i's ----
    if (tid < SI){
        int i = i0 + tid;
        float fi = img[i];
        float qi;
        if (MODE == 0){
            qi = (mask[i]==0) ? 1.0f/(1.0f+__expf( LCLIP))
                              : 1.0f/(1.0f+__expf(-LCLIP));
        } else {
            float m = 0.f;
            #pragma unroll
            for (int s = 0; s < NSEG; ++s) m += pprev[s*NPIX + i];
            float kk;
            if (MODE == 1){
                kk = 0.f;
                #pragma unroll
                for (int s = 0; s < NSEG; ++s) kk += pksum[s*NPIX + i];
                if (jb == 0) ksum[i] = kk;             // persist (iteration-invariant)
            } else {
                kk = ksum[i];
            }
            float duv = (mask[i]==0) ? LCLIP : -LCLIP;
            float mnd = m - 13.0f*qprev[i];            // remove diagonal
            float delta = duv + (kk - 13.0f) - 2.0f*mnd;
            qi = 1.0f/(1.0f+__expf(delta));
        }
        float xf = (float)(tid % IMW);
        st[tid/IMW][tid%IMW] = make_float4(fi, fmaf(C2*xf, xf, C3*fi*fi), 10.0f*qi, qi);
        if (jb == 0) qcur[i] = qi;                     // designated writer
    }

    // ---- per-j setup (register-only; overlaps the barrier) ----
    const int j   = jb*TB + tid;
    const int xji = j % IMW;
    const int yi  = j / IMW;
    const float xjf = (float)xji, fj = img[j];
    const float gx = -2.0f*C2*xjf;
    const float gf = -2.0f*C3*fj;
    const float bb = fmaf(C2*xjf, xjf, C3*fj*fj);
    const float dy0 = (float)(2*seg    ) - (float)yi;
    const float dy1 = (float)(2*seg + 1) - (float)yi;
    const float rc0 = fmaf(C2*dy0, dy0, bb);
    const float rc1 = fmaf(C2*dy1, dy1, bb);
    const float gy0 = exp2f(C1*dy0*dy0);
    const float gy1 = exp2f(C1*dy1*dy1);
    __syncthreads();

    // ---- phase 2: per-row gaussian 1D conv (shared across all j with same xj) ----
    if (tid < 192){
        int r = tid / IMW, x = tid - r*IMW;
        float c = 0.f;
        #pragma unroll 4
        for (int xp = 0; xp < IMW; ++xp)
            c = fmaf(st[r][xp].w, wg[x - xp + 95], c);
        conv[r][x] = c;
        if (MODE == 0 && r == 0){
            float sw = 0.f;
            #pragma unroll 4
            for (int xp = 0; xp < IMW; ++xp) sw += wg[x - xp + 95];
            sx3[x] = sw;
        }
    }
    __syncthreads();

    // ---- phase 3: dense bilateral partial matvec (~14 VALU/pair, no trans) ----
    float acc = 0.f, ak = 0.f;
    {
        float xf = 0.f;
        #pragma unroll 8
        for (int x = 0; x < IMW; ++x){
            float4 s = st[0][x];                       // wave-uniform broadcast
            float h = fmaf(xf, gx, fmaf(s.x, gf, s.y + rc0));
            float e = fexp2(h);
            acc = fmaf(s.z, e, acc);
            if (MODE == 0) ak += e;
            xf += 1.f;
        }
        xf = 0.f;
        #pragma unroll 8
        for (int x = 0; x < IMW; ++x){
            float4 s = st[1][x];
            float h = fmaf(xf, gx, fmaf(s.x, gf, s.y + rc1));
            float e = fexp2(h);
            acc = fmaf(s.z, e, acc);
            if (MODE == 0) ak += e;
            xf += 1.f;
        }
    }

    // ---- fold gaussian + store partials ----
    {
        float v = acc;
        v = fmaf(gy0, conv[0][xji], v);
        v = fmaf(gy1, conv[1][xji], v);
        pcur[seg*NPIX + j] = v;
        if (MODE == 0)
            pksum[seg*NPIX + j] = fmaf(10.0f, ak, (gy0+gy1)*sx3[xji]);
    }
}

// epilogue: final reduction + argmax
__global__ __launch_bounds__(TB) void k_final(const int* __restrict__ mask,
                                              const float* __restrict__ pmsg,
                                              const float* __restrict__ ksum,
                                              const float* __restrict__ qprev,
                                              float* __restrict__ out){
    int j = blockIdx.x*TB + threadIdx.x;
    float m = 0.f;
    #pragma unroll
    for (int s = 0; s < NSEG; ++s) m += pmsg[s*NPIX + j];
    float duv = (mask[j]==0) ? LCLIP : -LCLIP;
    float mnd = m - 13.0f*qprev[j];
    float delta = duv + (ksum[j] - 13.0f) - 2.0f*mnd;
    out[j] = (delta > 0.f) ? 1.0f : 0.0f;              // argmax; tie -> label 0
}

extern "C" void kernel_launch(void* const* d_in, const int* in_sizes, int n_in,
                              void* d_out, int out_size, void* d_ws, size_t ws_size,
                              hipStream_t stream){
    const float* img  = (const float*)d_in[0];
    const int*   mask = (const int*)d_in[1];
    float* out = (float*)d_out;
    float* ws  = (float*)d_ws;

    float* pmsgA = ws;                              // partials, even iters
    float* pmsgB = pmsgA + (size_t)NSEG*NPIX;       // partials, odd iters
    float* pksum = pmsgB + (size_t)NSEG*NPIX;       // per-seg column sums of Kfull
    float* qA    = pksum + (size_t)NSEG*NPIX;
    float* qB    = qA + NPIX;
    float* ksum  = qB + NPIX;                       // reduced column sums (persisted)

    dim3 g(NBIL), b(TB);
    // t=0: q_0 from mask; writes pmsgA, pksum, qA
    k_iter<0><<<g, b, 0, stream>>>(img, mask, nullptr, pmsgA, pksum, ksum, nullptr, qA);
    // t=1: full reconstruction (reduces pksum, persists ksum)
    k_iter<1><<<g, b, 0, stream>>>(img, mask, pmsgA, pmsgB, pksum, ksum, qA, qB);
    // t=2..4: slim reconstruction (reads reduced ksum)
    k_iter<2><<<g, b, 0, stream>>>(img, mask, pmsgB, pmsgA, pksum, ksum, qB, qA);
    k_iter<2><<<g, b, 0, stream>>>(img, mask, pmsgA, pmsgB, pksum, ksum, qA, qB);
    k_iter<2><<<g, b, 0, stream>>>(img, mask, pmsgB, pmsgA, pksum, ksum, qB, qA);
    // t=5: final update + argmax
    k_final<<<dim3(NUPD), b, 0, stream>>>(mask, pmsgA, ksum, qA, out);
}

// Round 9
// 162.093 us; speedup vs baseline: 1.7436x; 1.0690x over previous
//
#include <hip/hip_runtime.h>

constexpr int IMW  = 96;
constexpr int NPIX = 9216;
constexpr int TB   = 256;            // threads per block
constexpr int JB   = NPIX/TB;        // 36 j-blocks (JT=1)
constexpr int SI   = 192;            // staged i's per segment (2 rows)
constexpr int NSEG = NPIX/SI;        // 48 segments (partials stay L2-resident)
constexpr int NBIL = JB*NSEG;        // 1728 blocks
constexpr int NUPD = NPIX/TB;        // 36 blocks (epilogue)

constexpr float LCLIP = 18.420681f;               // -log(1e-8)
constexpr float LOG2E = 1.4426950408889634f;
constexpr float C1 = -LOG2E/18.0f;                // gaussian (sxy=3), base-2
constexpr float C2 = -LOG2E/5000.0f;              // bilateral spatial (sxy=50)
constexpr float C3 = -LOG2E/400.0f;               // bilateral feature (2*df^2/(2*20^2))

typedef float v2f __attribute__((ext_vector_type(2)));

// packed software exp2 on 2 lanes-worth of data: poly ops become v_pk_fma_f32.
// deg-6 Taylor on [-0.5,0.5], rel err ~1.2e-7. ldexp handles underflow.
__device__ __forceinline__ v2f fexp2v(v2f a){
    float n0 = rintf(a.x), n1 = rintf(a.y);
    v2f f = a - (v2f){n0, n1};
    v2f p = (v2f)(1.5403530e-4f);
    p = __builtin_elementwise_fma(p, f, (v2f)(1.3333558e-3f));
    p = __builtin_elementwise_fma(p, f, (v2f)(9.6181291e-3f));
    p = __builtin_elementwise_fma(p, f, (v2f)(5.5504109e-2f));
    p = __builtin_elementwise_fma(p, f, (v2f)(2.4022651e-1f));
    p = __builtin_elementwise_fma(p, f, (v2f)(6.9314718e-1f));
    p = __builtin_elementwise_fma(p, f, (v2f)(1.0f));
    v2f e;
    e.x = ldexpf(p.x, (int)n0);
    e.y = ldexpf(p.y, (int)n1);
    return e;
}

// One launch = one mean-field iteration. Segment = 2 image rows (SI=192).
// MODE 0: q_t from mask; also writes pksum. MODE 1: reconstruct q_t, persist ksum.
// MODE 2: reconstruct q_t, read reduced ksum.
// pcur[seg][j] = [dense bilateral, rows packed as float2] + gy0*conv0[xj] + gy1*conv1[xj]
template<int MODE>
__global__ __launch_bounds__(TB) void k_iter(const float* __restrict__ img,
                                             const int* __restrict__ mask,
                                             const float* __restrict__ pprev,
                                             float* __restrict__ pcur,
                                             float* __restrict__ pksum,
                                             float* __restrict__ ksum,
                                             const float* __restrict__ qprev,
                                             float* __restrict__ qcur){
    __shared__ __align__(16) float stf[IMW*4];   // per col x: {f_r0, f_r1, q_r0, q_r1}
    __shared__ float wg[192];                    // 3*exp2(C1*d^2), d = idx-95
    __shared__ float conv[2][IMW];               // per-row gaussian 1D conv of q
    __shared__ float sx3[IMW];                   // row-sum of wg (MODE0 only)
    const int tid = threadIdx.x;
    const int jb  = blockIdx.x / NSEG;
    const int seg = blockIdx.x % NSEG;
    const int i0  = seg * SI;

    if (tid < 192){
        float d = (float)(tid - 95);
        wg[tid] = 3.0f * exp2f(C1*d*d);
    }

    // ---- phase 1: q_t at this block's 192 staged i's ----
    if (tid < SI){
        int i = i0 + tid;
        float fi = img[i];
        float qi;
        if (MODE == 0){
            qi = (mask[i]==0) ? 1.0f/(1.0f+__expf( LCLIP))
                              : 1.0f/(1.0f+__expf(-LCLIP));
        } else {
            float m = 0.f;
            #pragma unroll
            for (int s = 0; s < NSEG; ++s) m += pprev[s*NPIX + i];
            float kk;
            if (MODE == 1){
                kk = 0.f;
                #pragma unroll
                for (int s = 0; s < NSEG; ++s) kk += pksum[s*NPIX + i];
                if (jb == 0) ksum[i] = kk;             // persist (iteration-invariant)
            } else {
                kk = ksum[i];
            }
            float duv = (mask[i]==0) ? LCLIP : -LCLIP;
            float mnd = m - 13.0f*qprev[i];            // remove diagonal
            float delta = duv + (kk - 13.0f) - 2.0f*mnd;
            qi = 1.0f/(1.0f+__expf(delta));
        }
        int r = tid / IMW, x = tid - r*IMW;
        stf[x*4 + r]     = fi;
        stf[x*4 + 2 + r] = qi;
        if (jb == 0) qcur[i] = qi;                     // designated writer
    }

    // ---- per-j setup (register-only; overlaps the barrier) ----
    const int j   = jb*TB + tid;
    const int xji = j % IMW;
    const int yi  = j / IMW;
    const float xjf = (float)xji, fj = img[j];
    const float gx = -2.0f*C2*xjf;
    const float gf = -2.0f*C3*fj;
    const float bb = fmaf(C2*xjf, xjf, C3*fj*fj);
    const float dy0 = (float)(2*seg    ) - (float)yi;
    const float dy1 = (float)(2*seg + 1) - (float)yi;
    const float gy0 = exp2f(C1*dy0*dy0);
    const float gy1 = exp2f(C1*dy1*dy1);
    __syncthreads();

    // ---- phase 2: per-row gaussian 1D conv (shared across all j with same xj) ----
    if (tid < 192){
        int r = tid / IMW, x = tid - r*IMW;
        float c = 0.f;
        #pragma unroll 4
        for (int xp = 0; xp < IMW; ++xp)
            c = fmaf(stf[xp*4 + 2 + r], wg[x - xp + 95], c);
        conv[r][x] = c;
        if (MODE == 0 && r == 0){
            float sw = 0.f;
            #pragma unroll 4
            for (int xp = 0; xp < IMW; ++xp) sw += wg[x - xp + 95];
            sx3[x] = sw;
        }
    }
    __syncthreads();

    // ---- phase 3: dense bilateral matvec, 2 rows packed per float2 (v_pk_fma) ----
    // h_r(x) = A_r(x) + f_i*(C3*f_i + gf),  A_r(x) = rc_r + gx*x + C2*x^2
    // forward difference: A += d; d += 2*C2  (packed, both rows share d)
    v2f asp = { fmaf(C2*dy0, dy0, bb), fmaf(C2*dy1, dy1, bb) };
    v2f dfd = (v2f)(gx + C2);
    const v2f ddd = (v2f)(2.0f*C2);
    const v2f gfv = (v2f)(gf);
    const v2f c3v = (v2f)(C3);
    v2f acc = (v2f)(0.f), ak = (v2f)(0.f);
    const float4* st4 = (const float4*)stf;
    #pragma unroll 8
    for (int x = 0; x < IMW; ++x){
        float4 s = st4[x];                             // wave-uniform broadcast b128
        v2f f2 = {s.x, s.y};
        v2f q2 = {s.z, s.w};
        v2f t2 = __builtin_elementwise_fma(c3v, f2, gfv);   // C3*f + gf
        v2f h2 = __builtin_elementwise_fma(f2, t2, asp);
        v2f e2 = fexp2v(h2);
        acc = __builtin_elementwise_fma(q2, e2, acc);
        if (MODE == 0) ak = ak + e2;
        asp = asp + dfd;
        dfd = dfd + ddd;
    }

    // ---- fold gaussian + store partials ----
    {
        float v = 10.0f*(acc.x + acc.y);               // compat_b
        v = fmaf(gy0, conv[0][xji], v);
        v = fmaf(gy1, conv[1][xji], v);
        pcur[seg*NPIX + j] = v;
        if (MODE == 0)
            pksum[seg*NPIX + j] = fmaf(10.0f, ak.x + ak.y, (gy0+gy1)*sx3[xji]);
    }
}

// epilogue: final reduction + argmax
__global__ __launch_bounds__(TB) void k_final(const int* __restrict__ mask,
                                              const float* __restrict__ pmsg,
                                              const float* __restrict__ ksum,
                                              const float* __restrict__ qprev,
                                              float* __restrict__ out){
    int j = blockIdx.x*TB + threadIdx.x;
    float m = 0.f;
    #pragma unroll
    for (int s = 0; s < NSEG; ++s) m += pmsg[s*NPIX + j];
    float duv = (mask[j]==0) ? LCLIP : -LCLIP;
    float mnd = m - 13.0f*qprev[j];
    float delta = duv + (ksum[j] - 13.0f) - 2.0f*mnd;
    out[j] = (delta > 0.f) ? 1.0f : 0.0f;              // argmax; tie -> label 0
}

extern "C" void kernel_launch(void* const* d_in, const int* in_sizes, int n_in,
                              void* d_out, int out_size, void* d_ws, size_t ws_size,
                              hipStream_t stream){
    const float* img  = (const float*)d_in[0];
    const int*   mask = (const int*)d_in[1];
    float* out = (float*)d_out;
    float* ws  = (float*)d_ws;

    float* pmsgA = ws;                              // partials, even iters
    float* pmsgB = pmsgA + (size_t)NSEG*NPIX;       // partials, odd iters
    float* pksum = pmsgB + (size_t)NSEG*NPIX;       // per-seg column sums of Kfull
    float* qA    = pksum + (size_t)NSEG*NPIX;
    float* qB    = qA + NPIX;
    float* ksum  = qB + NPIX;                       // reduced column sums (persisted)

    dim3 g(NBIL), b(TB);
    // t=0: q_0 from mask; writes pmsgA, pksum, qA
    k_iter<0><<<g, b, 0, stream>>>(img, mask, nullptr, pmsgA, pksum, ksum, nullptr, qA);
    // t=1: full reconstruction (reduces pksum, persists ksum)
    k_iter<1><<<g, b, 0, stream>>>(img, mask, pmsgA, pmsgB, pksum, ksum, qA, qB);
    // t=2..4: slim reconstruction (reads reduced ksum)
    k_iter<2><<<g, b, 0, stream>>>(img, mask, pmsgB, pmsgA, pksum, ksum, qB, qA);
    k_iter<2><<<g, b, 0, stream>>>(img, mask, pmsgA, pmsgB, pksum, ksum, qA, qB);
    k_iter<2><<<g, b, 0, stream>>>(img, mask, pmsgB, pmsgA, pksum, ksum, qB, qA);
    // t=5: final update + argmax
    k_final<<<dim3(NUPD), b, 0, stream>>>(mask, pmsgA, ksum, qA, out);
}